// Round 6
// baseline (145.595 us; speedup 1.0000x reference)
//
#include <hip/hip_runtime.h>
#include <math.h>

#define HDIM 256
#define H4   64          // HDIM / 4
#define EPSN 1e-8f       // torch F.cosine_similarity norm clamp
#define CT   80          // c-tile per block
#define GP   (CT/4)      // 20 c's per top-8 scan group
#define KC   8           // f4 k-steps per chunk (32 floats)
#define NCH  8           // chunks: KC*NCH = H4
#define TPB  256
#define GRID 256

typedef unsigned long long u64;
typedef unsigned int       u32;

// Monotonic (value, index) packing: larger key == better candidate under
// lax.top_k semantics (descending value, lower index wins ties).
__device__ __forceinline__ u64 make_key(float v, int idx) {
    u32 u = __float_as_uint(v);
    u ^= (u & 0x80000000u) ? 0xFFFFFFFFu : 0x80000000u;
    return ((u64)u << 32) | (u32)(~idx);
}
__device__ __forceinline__ float key_val(u64 k) {
    u32 u = (u32)(k >> 32);
    u ^= (u & 0x80000000u) ? 0x80000000u : 0xFFFFFFFFu;
    return __uint_as_float(u);
}
__device__ __forceinline__ int key_idx(u64 k) { return (int)(~(u32)k); }

__device__ __forceinline__ void insert8(u64* ls, u64 k) {
    if (k > ls[7]) {
        ls[7] = k;
        #pragma unroll
        for (int j = 7; j > 0; --j)
            if (ls[j] > ls[j-1]) { u64 tmp = ls[j]; ls[j] = ls[j-1]; ls[j-1] = tmp; }
    }
}

// Device-scope grid barrier. Counter slot is memset to 0 by the host each
// call (captured in the graph -> every replay starts clean). All GRID blocks
// are co-resident (LDS 20.7KB, 4 waves -> >=2 blocks/CU capacity), so the
// spin cannot deadlock. __threadfence before arrival publishes this block's
// writes; the post-barrier __threadfence (all threads) invalidates stale
// cache lines before reading other blocks' data (cross-XCD safety, G16).
__device__ __forceinline__ void grid_barrier(u32* ctr, u32 target) {
    __syncthreads();
    if (threadIdx.x == 0) {
        __threadfence();
        __hip_atomic_fetch_add(ctr, 1u, __ATOMIC_ACQ_REL, __HIP_MEMORY_SCOPE_AGENT);
        while (__hip_atomic_load(ctr, __ATOMIC_ACQUIRE, __HIP_MEMORY_SCOPE_AGENT) < target)
            __builtin_amdgcn_s_sleep(2);
    }
    __syncthreads();
    __threadfence();
}

// is_compressed storage-layout detection (logic validated rounds 1-5):
// lo -> nonzero byte at offset i%4!=0 => 1-byte layout
// lg -> any byte > 1               => float32 layout; neither => int32.
__device__ __forceinline__ void detect_mask(const void* is_comp, int C,
                                            int dt, int DT, int* flags) {
    const u32* mask4 = (const u32*)is_comp;
    const int n4 = C >> 2;
    int lo = 0, lg = 0;
    for (int i = dt; i < n4; i += DT) {
        u32 v = mask4[i];
        if (v & 0xFFFFFF00u) lo = 1;
        if (v & 0xFEFEFEFEu) lg = 1;
    }
    const unsigned char* mb = (const unsigned char*)is_comp;
    for (int j = (n4 << 2) + dt; j < C; j += DT) {
        unsigned char v = mb[j];
        if (v > 1) lg = 1;
        if ((j & 3) != 0 && v != 0) lo = 1;
    }
    lo = __any(lo); lg = __any(lg);
    if ((threadIdx.x & 63) == 0) {
        if (lo) atomicOr(&flags[0], 1);
        if (lg) atomicOr(&flags[1], 1);
    }
}

__global__ __launch_bounds__(TPB)
void fused_kernel(const float4* __restrict__ q4, const float4* __restrict__ emb4,
                  const float* __restrict__ episodes,
                  const float* __restrict__ compressed,
                  const void* __restrict__ is_comp,
                  float* __restrict__ out, float* __restrict__ scores_out,
                  u64* __restrict__ cand, int* __restrict__ top_idx,
                  int* __restrict__ flags, u32* __restrict__ ctr,
                  int C, int B, int S, int Cs, int NT) {
    __shared__ union {
        struct { float4 e[CT][KC + 1]; float4 q[64][KC + 1]; } st;  // 20736 B
        float sc[64][CT + 1];                                       // 20736 B
        u64   sh[TPB * 8];                                          // 16384 B
    } sm;

    const int t   = threadIdx.x;
    const int bid = blockIdx.x;
    const int nb  = gridDim.x;
    const float4 z = make_float4(0.f, 0.f, 0.f, 0.f);

    // ======================= Phase A: sims + local top-8 =======================
    if (bid < NT) {
        for (int tile = bid; tile < NT; tile += nb) {
            const int c0 = tile * CT;
            const int tc = t & 15;       // c-rows: tc + 16i, i < 5
            const int tb = t >> 4;       // b-rows: tb + 16j, j < 4
            float4 pe0, pe1, pe2, pq0, pq1;

            #define LOAD_E(idx, ch, dst) do {                                    \
                int _r = (idx) >> 3, _cl = (idx) & 7; int _gc = c0 + _r;         \
                dst = (_gc < C) ? emb4[(size_t)_gc * H4 + (ch) * KC + _cl] : z;  \
            } while (0)
            #define LOAD_Q(idx, ch, dst) do {                                    \
                int _r = (idx) >> 3, _cl = (idx) & 7;                            \
                dst = (_r < B) ? q4[(size_t)_r * H4 + (ch) * KC + _cl] : z;      \
            } while (0)
            #define LOAD_CHUNK(ch) do {                                          \
                LOAD_E(t,       ch, pe0); LOAD_E(t + 256, ch, pe1);              \
                if (t < 128) LOAD_E(t + 512, ch, pe2);                           \
                LOAD_Q(t,       ch, pq0); LOAD_Q(t + 256, ch, pq1);              \
            } while (0)

            LOAD_CHUNK(0);

            float acc[5][4], ee[5], qq[4];
            #pragma unroll
            for (int i = 0; i < 5; ++i) {
                ee[i] = 0.f;
                #pragma unroll
                for (int j = 0; j < 4; ++j) acc[i][j] = 0.f;
            }
            #pragma unroll
            for (int j = 0; j < 4; ++j) qq[j] = 0.f;

            for (int ch = 0; ch < NCH; ++ch) {
                __syncthreads();
                { int r = t >> 3,       cl = t & 7;       sm.st.e[r][cl] = pe0; }
                { int r = (t+256) >> 3, cl = (t+256) & 7; sm.st.e[r][cl] = pe1; }
                if (t < 128) { int r = (t+512) >> 3, cl = (t+512) & 7; sm.st.e[r][cl] = pe2; }
                { int r = t >> 3,       cl = t & 7;       sm.st.q[r][cl] = pq0; }
                { int r = (t+256) >> 3, cl = (t+256) & 7; sm.st.q[r][cl] = pq1; }
                __syncthreads();

                if (ch + 1 < NCH) LOAD_CHUNK(ch + 1);

                #pragma unroll
                for (int s = 0; s < KC; ++s) {
                    float4 a[5], b[4];
                    #pragma unroll
                    for (int i = 0; i < 5; ++i) a[i] = sm.st.e[tc + 16 * i][s];
                    #pragma unroll
                    for (int j = 0; j < 4; ++j) b[j] = sm.st.q[tb + 16 * j][s];

                    #pragma unroll
                    for (int i = 0; i < 5; ++i)
                        ee[i] = fmaf(a[i].x,a[i].x, fmaf(a[i].y,a[i].y,
                                fmaf(a[i].z,a[i].z, fmaf(a[i].w,a[i].w, ee[i]))));
                    #pragma unroll
                    for (int j = 0; j < 4; ++j)
                        qq[j] = fmaf(b[j].x,b[j].x, fmaf(b[j].y,b[j].y,
                                fmaf(b[j].z,b[j].z, fmaf(b[j].w,b[j].w, qq[j]))));
                    #pragma unroll
                    for (int i = 0; i < 5; ++i)
                        #pragma unroll
                        for (int j = 0; j < 4; ++j)
                            acc[i][j] = fmaf(a[i].x,b[j].x, fmaf(a[i].y,b[j].y,
                                        fmaf(a[i].z,b[j].z, fmaf(a[i].w,b[j].w, acc[i][j]))));
                }
            }
            #undef LOAD_CHUNK
            #undef LOAD_Q
            #undef LOAD_E

            float einv[5], qinv[4];
            #pragma unroll
            for (int i = 0; i < 5; ++i) einv[i] = 1.f / fmaxf(sqrtf(ee[i]), EPSN);
            #pragma unroll
            for (int j = 0; j < 4; ++j) qinv[j] = 1.f / fmaxf(sqrtf(qq[j]), EPSN);

            __syncthreads();            // all waves done reading sm.st
            #pragma unroll
            for (int j = 0; j < 4; ++j)
                #pragma unroll
                for (int i = 0; i < 5; ++i)
                    sm.sc[tb + 16 * j][tc + 16 * i] = acc[i][j] * qinv[j] * einv[i];
            __syncthreads();

            // per-(b, 20-c-group) top-8 -> cand[tile][b][g*8..g*8+7]
            const int b = t & 63, g = t >> 6;
            u64 ls[8] = {0, 0, 0, 0, 0, 0, 0, 0};
            #pragma unroll
            for (int i2 = 0; i2 < GP; ++i2) {
                int cl = g * GP + i2;
                int c  = c0 + cl;
                if (c < C && b < B) insert8(ls, make_key(sm.sc[b][cl], c));
            }
            u64* dst = cand + ((size_t)tile * 64 + b) * 32 + g * 8;
            #pragma unroll
            for (int j2 = 0; j2 < 8; ++j2) dst[j2] = ls[j2];
            __syncthreads();            // before next tile reuses sm
        }
        if (bid == 0 && nb <= NT) detect_mask(is_comp, C, t, TPB, flags);
    } else {
        const int nd = nb - NT;
        detect_mask(is_comp, C, (bid - NT) * TPB + t, nd * TPB, flags);
    }

    grid_barrier(&ctr[0], nb);

    // ======================= Phase B: global top-8 merge =======================
    if (bid < B) {
        const int b = bid;
        const int total = NT * 32;
        const u64* cb = cand + (size_t)b * 32;
        const size_t tstride = (size_t)64 * 32;

        u64 ls[8] = {0, 0, 0, 0, 0, 0, 0, 0};
        int m = t;
        for (; m + 7 * TPB < total; m += 8 * TPB) {
            u64 v[8];
            #pragma unroll
            for (int u = 0; u < 8; ++u) {
                int mm = m + u * TPB;
                v[u] = cb[(size_t)(mm >> 5) * tstride + (mm & 31)];
            }
            #pragma unroll
            for (int u = 0; u < 8; ++u) insert8(ls, v[u]);
        }
        for (; m < total; m += TPB)
            insert8(ls, cb[(size_t)(m >> 5) * tstride + (m & 31)]);

        #pragma unroll
        for (int j = 0; j < 8; ++j) sm.sh[t * 8 + j] = ls[j];
        __syncthreads();

        if (t < 64) {
            u64 mreg[8];
            #pragma unroll
            for (int j = 0; j < 8; ++j) mreg[j] = 0ull;
            for (int tt = 0; tt < 4; ++tt) {
                const u64* p = &sm.sh[(t * 4 + tt) * 8];
                #pragma unroll
                for (int j = 0; j < 8; ++j) {
                    u64 k = p[j];
                    if (k <= mreg[7]) break;        // p[] sorted descending
                    mreg[7] = k;
                    #pragma unroll
                    for (int q = 7; q > 0; --q)
                        if (mreg[q] > mreg[q-1]) { u64 tmp = mreg[q]; mreg[q] = mreg[q-1]; mreg[q-1] = tmp; }
                }
            }
            for (int r = 0; r < 8; ++r) {
                u64 best = mreg[0];
                #pragma unroll
                for (int off = 32; off; off >>= 1) {
                    u64 o = __shfl_xor(best, off, 64);
                    if (o > best) best = o;
                }
                if (mreg[0] == best) {              // unique owner pops
                    #pragma unroll
                    for (int q = 0; q < 7; ++q) mreg[q] = mreg[q+1];
                    mreg[7] = 0ull;
                }
                if (t == 0) {
                    scores_out[b * 8 + r] = key_val(best);
                    top_idx[b * 8 + r]    = key_idx(best);
                }
            }
        }
    }

    grid_barrier(&ctr[1], nb);

    // ======================= Phase C: gather =======================
    const int f_off = flags[0], f_gt1 = flags[1];
    const int n4   = S * H4;       // 2048
    const int c4   = Cs * H4;      // 1024
    const int half = n4 >> 1;      // 1024
    const int units = B * 8 * 2;   // 1024 half-episode copies

    for (int u = bid; u < units; u += nb) {
        const int bj  = u >> 1;
        const int h   = u & 1;
        const int idx = top_idx[bj];

        bool comp;
        if      (f_gt1) comp = ((const float*)is_comp)[idx] != 0.f;
        else if (f_off) comp = ((const unsigned char*)is_comp)[idx] != 0;
        else            comp = ((const int*)is_comp)[idx] != 0;

        const float4* full4 = (const float4*)episodes   + (size_t)idx * n4;
        const float4* cmp4  = (const float4*)compressed + (size_t)idx * c4;
        float4* out4 = (float4*)out + (size_t)bj * n4;
        const int v0 = h * half;

        if (comp) {
            #pragma unroll 4
            for (int v = v0 + t; v < v0 + half; v += TPB)
                out4[v] = (v < c4) ? cmp4[v] : z;
        } else {
            #pragma unroll 4
            for (int v = v0 + t; v < v0 + half; v += TPB)
                out4[v] = full4[v];
        }
    }
}

// ---------------------------------------------------------------------------
extern "C" void kernel_launch(void* const* d_in, const int* in_sizes, int n_in,
                              void* d_out, int out_size, void* d_ws, size_t ws_size,
                              hipStream_t stream) {
    const float* query      = (const float*)d_in[0];
    const float* episodes   = (const float*)d_in[1];
    const float* compressed = (const float*)d_in[2];
    const float* emb        = (const float*)d_in[3];
    const void*  is_comp    = d_in[4];
    // d_in[5] is k (device scalar); fixed at 8 by the problem setup.

    const int B  = in_sizes[0] / HDIM;        // 64
    const int C  = in_sizes[3] / HDIM;        // 20000
    const int S  = in_sizes[1] / (C * HDIM);  // 32
    const int Cs = in_sizes[2] / (C * HDIM);  // 16
    const int K  = 8;
    const int NT = (C + CT - 1) / CT;         // 250 tiles

    float* out        = (float*)d_out;
    float* scores_out = out + (size_t)B * K * S * HDIM;

    // ws layout (ctr+flags memset each call -> replay-safe; rest fully
    // rewritten every call):
    char* ws      = (char*)d_ws;
    u32*  ctr     = (u32*)ws;                 // 2 x u32   (barrier slots)
    int*  flags   = (int*)(ws + 8);           // 2 x int   (mask layout)
    int*  top_idx = (int*)(ws + 64);          // B*K ints
    u64*  cand    = (u64*)(ws + 4096);        // NT*64*32 u64 = 4.1 MB

    hipMemsetAsync(d_ws, 0, 16, stream);
    fused_kernel<<<GRID, TPB, 0, stream>>>(
        (const float4*)query, (const float4*)emb, episodes, compressed, is_comp,
        out, scores_out, cand, top_idx, flags, ctr, C, B, S, Cs, NT);
}

// Round 7
// 92.163 us; speedup vs baseline: 1.5798x; 1.5798x over previous
//
#include <hip/hip_runtime.h>
#include <math.h>

#define HDIM 256
#define H4   64          // HDIM / 4
#define EPSN 1e-8f       // torch F.cosine_similarity norm clamp
#define CT   80          // c-tile per block -> grid = 250 blocks (no CU tail)
#define KC   8           // f4 k-steps per chunk (32 floats)
#define NCH  8           // chunks: KC*NCH = H4

typedef unsigned long long u64;
typedef unsigned int       u32;

// Monotonic (value, index) packing: larger key == better candidate under
// lax.top_k semantics (descending value, lower index wins ties).
__device__ __forceinline__ u64 make_key(float v, int idx) {
    u32 u = __float_as_uint(v);
    u ^= (u & 0x80000000u) ? 0xFFFFFFFFu : 0x80000000u;
    return ((u64)u << 32) | (u32)(~idx);
}
__device__ __forceinline__ float key_val(u64 k) {
    u32 u = (u32)(k >> 32);
    u ^= (u & 0x80000000u) ? 0x80000000u : 0xFFFFFFFFu;
    return __uint_as_float(u);
}
__device__ __forceinline__ int key_idx(u64 k) { return (int)(~(u32)k); }

// ---------------------------------------------------------------------------
// Kernel 1 (sims): 80c x 64b block tile, 5x4 register tile per lane.
// grid = 250 blocks -> 1 block/CU, no tail. K chunked 8 x 32 floats, rows
// padded to 9 f4. Next chunk prefetched to registers during compute. e-norms
// and q-norms fused into the accumulation. (Identical to round 5.)
// NOTE: this round launches sims TWICE (identical writes, deterministic) to
// attribute its cost via the total-duration delta vs round 5's 67.8 us.
// ---------------------------------------------------------------------------
__global__ __launch_bounds__(256)
void sims_kernel(const float4* __restrict__ q4, const float4* __restrict__ emb4,
                 float* __restrict__ sims, int C, int B) {
    __shared__ float4 e_lds[CT][KC + 1];   // 80 x 9 f4 = 11.5 KB
    __shared__ float4 q_lds[64][KC + 1];   // 64 x 9 f4 =  9.2 KB

    const int t  = threadIdx.x;
    const int c0 = blockIdx.x * CT;
    const int tc = t & 15;       // c-rows: tc + 16i, i < 5
    const int tb = t >> 4;       // b-rows: tb + 16j, j < 4
    const float4 z = make_float4(0.f, 0.f, 0.f, 0.f);

    float4 pe0, pe1, pe2, pq0, pq1;

    #define LOAD_E(idx, ch, dst) do {                                        \
        int _r = (idx) >> 3, _cl = (idx) & 7; int _gc = c0 + _r;             \
        dst = (_gc < C) ? emb4[(size_t)_gc * H4 + (ch) * KC + _cl] : z;      \
    } while (0)
    #define LOAD_Q(idx, ch, dst) do {                                        \
        int _r = (idx) >> 3, _cl = (idx) & 7;                                \
        dst = (_r < B) ? q4[(size_t)_r * H4 + (ch) * KC + _cl] : z;          \
    } while (0)
    #define LOAD_CHUNK(ch) do {                                              \
        LOAD_E(t,       ch, pe0); LOAD_E(t + 256, ch, pe1);                  \
        if (t < 128) LOAD_E(t + 512, ch, pe2);                               \
        LOAD_Q(t,       ch, pq0); LOAD_Q(t + 256, ch, pq1);                  \
    } while (0)

    LOAD_CHUNK(0);

    float acc[5][4], ee[5], qq[4];
    #pragma unroll
    for (int i = 0; i < 5; ++i) {
        ee[i] = 0.f;
        #pragma unroll
        for (int j = 0; j < 4; ++j) acc[i][j] = 0.f;
    }
    #pragma unroll
    for (int j = 0; j < 4; ++j) qq[j] = 0.f;

    for (int ch = 0; ch < NCH; ++ch) {
        __syncthreads();                       // prev chunk's LDS reads done
        { int r = t >> 3,        cl = t & 7;        e_lds[r][cl] = pe0; }
        { int r = (t+256) >> 3,  cl = (t+256) & 7;  e_lds[r][cl] = pe1; }
        if (t < 128) { int r = (t+512) >> 3, cl = (t+512) & 7; e_lds[r][cl] = pe2; }
        { int r = t >> 3,        cl = t & 7;        q_lds[r][cl] = pq0; }
        { int r = (t+256) >> 3,  cl = (t+256) & 7;  q_lds[r][cl] = pq1; }
        __syncthreads();                       // stores visible

        if (ch + 1 < NCH) LOAD_CHUNK(ch + 1);  // prefetch overlaps compute

        #pragma unroll
        for (int s = 0; s < KC; ++s) {
            float4 a[5], b[4];
            #pragma unroll
            for (int i = 0; i < 5; ++i) a[i] = e_lds[tc + 16 * i][s];
            #pragma unroll
            for (int j = 0; j < 4; ++j) b[j] = q_lds[tb + 16 * j][s];

            #pragma unroll
            for (int i = 0; i < 5; ++i)
                ee[i] = fmaf(a[i].x,a[i].x, fmaf(a[i].y,a[i].y,
                        fmaf(a[i].z,a[i].z, fmaf(a[i].w,a[i].w, ee[i]))));
            #pragma unroll
            for (int j = 0; j < 4; ++j)
                qq[j] = fmaf(b[j].x,b[j].x, fmaf(b[j].y,b[j].y,
                        fmaf(b[j].z,b[j].z, fmaf(b[j].w,b[j].w, qq[j]))));
            #pragma unroll
            for (int i = 0; i < 5; ++i)
                #pragma unroll
                for (int j = 0; j < 4; ++j)
                    acc[i][j] = fmaf(a[i].x,b[j].x, fmaf(a[i].y,b[j].y,
                                fmaf(a[i].z,b[j].z, fmaf(a[i].w,b[j].w, acc[i][j]))));
        }
    }

    float einv[5], qinv[4];
    #pragma unroll
    for (int i = 0; i < 5; ++i) einv[i] = 1.f / fmaxf(sqrtf(ee[i]), EPSN);
    #pragma unroll
    for (int j = 0; j < 4; ++j) qinv[j] = 1.f / fmaxf(sqrtf(qq[j]), EPSN);

    #pragma unroll
    for (int j = 0; j < 4; ++j) {
        int b = tb + 16 * j;
        if (b < B) {
            #pragma unroll
            for (int i = 0; i < 5; ++i) {
                int c = c0 + tc + 16 * i;
                if (c < C) sims[(size_t)b * C + c] = acc[i][j] * qinv[j] * einv[i];
            }
        }
    }
    #undef LOAD_CHUNK
    #undef LOAD_Q
    #undef LOAD_E
}

// ---------------------------------------------------------------------------
// Kernel 2: blocks 0..B-1: per-row top-8. Scan phase uses 8-deep manual load
// batching. Last block: is_compressed storage-layout detection.
// (Identical to round 5.)
// ---------------------------------------------------------------------------
__global__ __launch_bounds__(256)
void topk_kernel(const float* __restrict__ sims, const u32* __restrict__ mask4,
                 float* __restrict__ scores_out, int* __restrict__ idx_out,
                 int* __restrict__ flags, int C) {
    const int t = threadIdx.x;

    if (blockIdx.x == gridDim.x - 1) {     // ---- mask layout detection ----
        __shared__ int red0[4], red1[4];
        int lo = 0, lg = 0;
        const int n4 = C >> 2;
        int i = t;
        for (; i + 768 < n4; i += 1024) {
            u32 v0 = mask4[i], v1 = mask4[i + 256], v2 = mask4[i + 512], v3 = mask4[i + 768];
            u32 o = v0 | v1 | v2 | v3;
            if (o & 0xFFFFFF00u) lo = 1;   // nonzero byte at offset 1..3
            if (o & 0xFEFEFEFEu) lg = 1;   // any byte value > 1
        }
        for (; i < n4; i += 256) {
            u32 v = mask4[i];
            if (v & 0xFFFFFF00u) lo = 1;
            if (v & 0xFEFEFEFEu) lg = 1;
        }
        const unsigned char* mb = (const unsigned char*)mask4;
        for (int j = (n4 << 2) + t; j < C; j += 256) {
            unsigned char v = mb[j];
            if (v > 1) lg = 1;
            if ((j & 3) != 0 && v != 0) lo = 1;
        }
        lo = __any(lo); lg = __any(lg);
        if ((t & 63) == 0) { red0[t >> 6] = lo; red1[t >> 6] = lg; }
        __syncthreads();
        if (t == 0) {
            flags[0] = red0[0] | red0[1] | red0[2] | red0[3];
            flags[1] = red1[0] | red1[1] | red1[2] | red1[3];
        }
        return;
    }

    __shared__ u64 sh[256 * 8];   // 16 KB
    const int b = blockIdx.x;
    const float* row = sims + (size_t)b * C;

    u64 ls[8];
    #pragma unroll
    for (int j = 0; j < 8; ++j) ls[j] = 0ull;

    #define INSERT(KEY) do {                                                  \
        u64 _k = (KEY);                                                       \
        if (_k > ls[7]) {                                                     \
            ls[7] = _k;                                                       \
            _Pragma("unroll")                                                 \
            for (int _j = 7; _j > 0; --_j)                                    \
                if (ls[_j] > ls[_j-1]) { u64 _t = ls[_j]; ls[_j] = ls[_j-1]; ls[_j-1] = _t; } \
        }                                                                     \
    } while (0)

    int c = t;
    for (; c + 7 * 256 < C; c += 8 * 256) {        // 8 independent loads first
        float v[8];
        #pragma unroll
        for (int u = 0; u < 8; ++u) v[u] = row[c + u * 256];
        #pragma unroll
        for (int u = 0; u < 8; ++u) INSERT(make_key(v[u], c + u * 256));
    }
    for (; c < C; c += 256) INSERT(make_key(row[c], c));
    #undef INSERT

    #pragma unroll
    for (int j = 0; j < 8; ++j) sh[t * 8 + j] = ls[j];
    __syncthreads();

    if (t < 64) {
        u64 m[8];
        #pragma unroll
        for (int j = 0; j < 8; ++j) m[j] = 0ull;
        for (int tt = 0; tt < 4; ++tt) {
            const u64* p = &sh[(t * 4 + tt) * 8];
            #pragma unroll
            for (int j = 0; j < 8; ++j) {
                u64 k = p[j];
                if (k <= m[7]) break;           // p[] sorted descending
                m[7] = k;
                #pragma unroll
                for (int q = 7; q > 0; --q)
                    if (m[q] > m[q-1]) { u64 tmp = m[q]; m[q] = m[q-1]; m[q-1] = tmp; }
            }
        }
        for (int r = 0; r < 8; ++r) {
            u64 best = m[0];
            #pragma unroll
            for (int off = 32; off; off >>= 1) {
                u64 o = __shfl_xor(best, off, 64);
                if (o > best) best = o;
            }
            if (m[0] == best) {                 // unique owner pops
                #pragma unroll
                for (int q = 0; q < 7; ++q) m[q] = m[q+1];
                m[7] = 0ull;
            }
            if (t == 0) {
                scores_out[b * 8 + r] = key_val(best);
                idx_out[b * 8 + r]    = key_idx(best);
            }
        }
    }
}

// ---------------------------------------------------------------------------
// Kernel 3: gather. TWO blocks per (b, j): each copies half an episode.
// (Identical to round 5.)
// ---------------------------------------------------------------------------
__global__ __launch_bounds__(256)
void gather_kernel(const float* __restrict__ episodes,    // [C][S][256]
                   const float* __restrict__ compressed,  // [C][Cs][256]
                   const void* __restrict__ is_comp,
                   const int* __restrict__ top_idx,       // [B*8]
                   const int* __restrict__ flags,
                   float* __restrict__ out,               // [B*8][S*256]
                   int S, int Cs) {
    const int bj  = blockIdx.x >> 1;
    const int h   = blockIdx.x & 1;
    const int idx = top_idx[bj];
    const int f_off = flags[0], f_gt1 = flags[1];

    bool comp;
    if      (f_gt1) comp = ((const float*)is_comp)[idx] != 0.f;
    else if (f_off) comp = ((const unsigned char*)is_comp)[idx] != 0;
    else            comp = ((const int*)is_comp)[idx] != 0;

    const int n4   = S * H4;       // 2048
    const int c4   = Cs * H4;      // 1024
    const int half = n4 >> 1;      // 1024
    const int v0   = h * half;     // this block's range [v0, v0+half)

    const float4* full4 = (const float4*)episodes   + (size_t)idx * n4;
    const float4* cmp4  = (const float4*)compressed + (size_t)idx * c4;
    float4* out4 = (float4*)out + (size_t)bj * n4;
    const float4 z = make_float4(0.f, 0.f, 0.f, 0.f);

    if (comp) {
        #pragma unroll 4
        for (int v = v0 + threadIdx.x; v < v0 + half; v += 256)
            out4[v] = (v < c4) ? cmp4[v] : z;
    } else {
        #pragma unroll 4
        for (int v = v0 + threadIdx.x; v < v0 + half; v += 256)
            out4[v] = full4[v];
    }
}

// ---------------------------------------------------------------------------
extern "C" void kernel_launch(void* const* d_in, const int* in_sizes, int n_in,
                              void* d_out, int out_size, void* d_ws, size_t ws_size,
                              hipStream_t stream) {
    const float* query      = (const float*)d_in[0];
    const float* episodes   = (const float*)d_in[1];
    const float* compressed = (const float*)d_in[2];
    const float* emb        = (const float*)d_in[3];
    const void*  is_comp    = d_in[4];
    // d_in[5] is k (device scalar); fixed at 8 by the problem setup.

    const int B  = in_sizes[0] / HDIM;        // 64
    const int C  = in_sizes[3] / HDIM;        // 20000
    const int S  = in_sizes[1] / (C * HDIM);  // 32
    const int Cs = in_sizes[2] / (C * HDIM);  // 16
    const int K  = 8;

    float* out        = (float*)d_out;
    float* scores_out = out + (size_t)B * K * S * HDIM;

    // scratch layout in d_ws (fully rewritten every call -> deterministic):
    float* sims    = (float*)d_ws;                             // B*C floats
    size_t simsOff = (((size_t)B * C * sizeof(float)) + 255) & ~(size_t)255;
    int*   top_idx = (int*)((char*)d_ws + simsOff);            // B*K ints
    int*   flags   = top_idx + B * K;                          // 2 ints

    // ATTRIBUTION ROUND: sims launched TWICE (identical writes, deterministic).
    // total_dur - 67.8us (round-5 baseline) == true cost of one sims pass.
    sims_kernel<<<(C + CT - 1) / CT, 256, 0, stream>>>(
        (const float4*)query, (const float4*)emb, sims, C, B);
    sims_kernel<<<(C + CT - 1) / CT, 256, 0, stream>>>(
        (const float4*)query, (const float4*)emb, sims, C, B);
    topk_kernel<<<B + 1, 256, 0, stream>>>(sims, (const u32*)is_comp,
                                           scores_out, top_idx, flags, C);
    gather_kernel<<<B * K * 2, 256, 0, stream>>>(episodes, compressed, is_comp,
                                                 top_idx, flags, out, S, Cs);
}

// Round 8
// 55.422 us; speedup vs baseline: 2.6270x; 1.6629x over previous
//
#include <hip/hip_runtime.h>
#include <math.h>

#define HDIM 256
#define H4   64          // HDIM / 4
#define EPSN 1e-8f       // torch F.cosine_similarity norm clamp
#define CT   80          // c-tile per block -> grid = 250 blocks (no CU tail)
#define KC   8           // f4 k-steps per chunk (32 floats)
#define NCH  8           // chunks: KC*NCH = H4

typedef unsigned long long u64;
typedef unsigned int       u32;

// Monotonic (value, index) packing: larger key == better candidate under
// lax.top_k semantics (descending value, lower index wins ties).
__device__ __forceinline__ u64 make_key(float v, int idx) {
    u32 u = __float_as_uint(v);
    u ^= (u & 0x80000000u) ? 0xFFFFFFFFu : 0x80000000u;
    return ((u64)u << 32) | (u32)(~idx);
}
__device__ __forceinline__ float key_val(u64 k) {
    u32 u = (u32)(k >> 32);
    u ^= (u & 0x80000000u) ? 0x80000000u : 0xFFFFFFFFu;
    return __uint_as_float(u);
}
__device__ __forceinline__ int key_idx(u64 k) { return (int)(~(u32)k); }

__device__ __forceinline__ void insert8(u64* ls, u64 k) {
    if (k > ls[7]) {
        ls[7] = k;
        #pragma unroll
        for (int j = 7; j > 0; --j)
            if (ls[j] > ls[j-1]) { u64 tmp = ls[j]; ls[j] = ls[j-1]; ls[j-1] = tmp; }
    }
}

// ---------------------------------------------------------------------------
// Kernel 1 (sims): 80c x 64b tile, 5x4 register tile, DOUBLE-BUFFERED LDS:
// one __syncthreads per K-chunk (was two). Chunk ch+1 is global-prefetched to
// regs during compute of ch, then ds_written to the OTHER buffer (no conflict
// with ongoing reads), barrier, switch. Per-accumulator FMA sequence is
// unchanged from rounds 4-7 -> bit-identical output.
// ---------------------------------------------------------------------------
__global__ __launch_bounds__(256)
void sims_kernel(const float4* __restrict__ q4, const float4* __restrict__ emb4,
                 float* __restrict__ sims, int C, int B) {
    __shared__ float4 e_lds[2][CT][KC + 1];   // 2 x 11.25 KB
    __shared__ float4 q_lds[2][64][KC + 1];   // 2 x  9.0 KB   (total 41.5 KB)

    const int t  = threadIdx.x;
    const int c0 = blockIdx.x * CT;
    const int tc = t & 15;       // c-rows: tc + 16i, i < 5
    const int tb = t >> 4;       // b-rows: tb + 16j, j < 4
    const float4 z = make_float4(0.f, 0.f, 0.f, 0.f);

    float4 pe0, pe1, pe2, pq0, pq1;

    #define LOAD_E(idx, ch, dst) do {                                        \
        int _r = (idx) >> 3, _cl = (idx) & 7; int _gc = c0 + _r;             \
        dst = (_gc < C) ? emb4[(size_t)_gc * H4 + (ch) * KC + _cl] : z;      \
    } while (0)
    #define LOAD_Q(idx, ch, dst) do {                                        \
        int _r = (idx) >> 3, _cl = (idx) & 7;                                \
        dst = (_r < B) ? q4[(size_t)_r * H4 + (ch) * KC + _cl] : z;          \
    } while (0)
    #define LOAD_CHUNK(ch) do {                                              \
        LOAD_E(t,       ch, pe0); LOAD_E(t + 256, ch, pe1);                  \
        if (t < 128) LOAD_E(t + 512, ch, pe2);                               \
        LOAD_Q(t,       ch, pq0); LOAD_Q(t + 256, ch, pq1);                  \
    } while (0)
    #define WRITE_CHUNK(pp) do {                                             \
        { int r = t >> 3,       cl = t & 7;       e_lds[pp][r][cl] = pe0; }  \
        { int r = (t+256) >> 3, cl = (t+256) & 7; e_lds[pp][r][cl] = pe1; }  \
        if (t < 128) { int r = (t+512) >> 3, cl = (t+512) & 7; e_lds[pp][r][cl] = pe2; } \
        { int r = t >> 3,       cl = t & 7;       q_lds[pp][r][cl] = pq0; }  \
        { int r = (t+256) >> 3, cl = (t+256) & 7; q_lds[pp][r][cl] = pq1; }  \
    } while (0)

    float acc[5][4], ee[5], qq[4];
    #pragma unroll
    for (int i = 0; i < 5; ++i) {
        ee[i] = 0.f;
        #pragma unroll
        for (int j = 0; j < 4; ++j) acc[i][j] = 0.f;
    }
    #pragma unroll
    for (int j = 0; j < 4; ++j) qq[j] = 0.f;

    LOAD_CHUNK(0);
    WRITE_CHUNK(0);
    __syncthreads();

    int p = 0;
    for (int ch = 0; ch < NCH; ++ch) {
        if (ch + 1 < NCH) LOAD_CHUNK(ch + 1);    // global prefetch (async)

        #pragma unroll
        for (int s = 0; s < KC; ++s) {
            float4 a[5], b[4];
            #pragma unroll
            for (int i = 0; i < 5; ++i) a[i] = e_lds[p][tc + 16 * i][s];
            #pragma unroll
            for (int j = 0; j < 4; ++j) b[j] = q_lds[p][tb + 16 * j][s];

            #pragma unroll
            for (int i = 0; i < 5; ++i)
                ee[i] = fmaf(a[i].x,a[i].x, fmaf(a[i].y,a[i].y,
                        fmaf(a[i].z,a[i].z, fmaf(a[i].w,a[i].w, ee[i]))));
            #pragma unroll
            for (int j = 0; j < 4; ++j)
                qq[j] = fmaf(b[j].x,b[j].x, fmaf(b[j].y,b[j].y,
                        fmaf(b[j].z,b[j].z, fmaf(b[j].w,b[j].w, qq[j]))));
            #pragma unroll
            for (int i = 0; i < 5; ++i)
                #pragma unroll
                for (int j = 0; j < 4; ++j)
                    acc[i][j] = fmaf(a[i].x,b[j].x, fmaf(a[i].y,b[j].y,
                                fmaf(a[i].z,b[j].z, fmaf(a[i].w,b[j].w, acc[i][j]))));
        }

        if (ch + 1 < NCH) {
            WRITE_CHUNK(p ^ 1);    // other buffer: no conflict with readers
            __syncthreads();       // single barrier per chunk
            p ^= 1;
        }
    }

    float einv[5], qinv[4];
    #pragma unroll
    for (int i = 0; i < 5; ++i) einv[i] = 1.f / fmaxf(sqrtf(ee[i]), EPSN);
    #pragma unroll
    for (int j = 0; j < 4; ++j) qinv[j] = 1.f / fmaxf(sqrtf(qq[j]), EPSN);

    #pragma unroll
    for (int j = 0; j < 4; ++j) {
        int b = tb + 16 * j;
        if (b < B) {
            #pragma unroll
            for (int i = 0; i < 5; ++i) {
                int c = c0 + tc + 16 * i;
                if (c < C) sims[(size_t)b * C + c] = acc[i][j] * qinv[j] * einv[i];
            }
        }
    }
    #undef WRITE_CHUNK
    #undef LOAD_CHUNK
    #undef LOAD_Q
    #undef LOAD_E
}

// ---------------------------------------------------------------------------
// Kernel 2 (topk_scan): grid = B*4 + 1. Blocks (b, seg): scan C/4 of row b
// (8-deep batched loads), per-thread top-8, block merge -> cand[b][seg][8].
// Last block: is_compressed storage-layout detection (validated rounds 1-7).
// ---------------------------------------------------------------------------
__global__ __launch_bounds__(256)
void topk_scan(const float* __restrict__ sims, const u32* __restrict__ mask4,
               u64* __restrict__ cand, int* __restrict__ flags, int C, int B) {
    const int t = threadIdx.x;

    if (blockIdx.x == (unsigned)(B * 4)) {   // ---- mask layout detection ----
        __shared__ int red0[4], red1[4];
        int lo = 0, lg = 0;
        const int n4 = C >> 2;
        int i = t;
        for (; i + 768 < n4; i += 1024) {
            u32 v0 = mask4[i], v1 = mask4[i + 256], v2 = mask4[i + 512], v3 = mask4[i + 768];
            u32 o = v0 | v1 | v2 | v3;
            if (o & 0xFFFFFF00u) lo = 1;   // nonzero byte at offset 1..3
            if (o & 0xFEFEFEFEu) lg = 1;   // any byte value > 1
        }
        for (; i < n4; i += 256) {
            u32 v = mask4[i];
            if (v & 0xFFFFFF00u) lo = 1;
            if (v & 0xFEFEFEFEu) lg = 1;
        }
        const unsigned char* mb = (const unsigned char*)mask4;
        for (int j = (n4 << 2) + t; j < C; j += 256) {
            unsigned char v = mb[j];
            if (v > 1) lg = 1;
            if ((j & 3) != 0 && v != 0) lo = 1;
        }
        lo = __any(lo); lg = __any(lg);
        if ((t & 63) == 0) { red0[t >> 6] = lo; red1[t >> 6] = lg; }
        __syncthreads();
        if (t == 0) {
            flags[0] = red0[0] | red0[1] | red0[2] | red0[3];
            flags[1] = red1[0] | red1[1] | red1[2] | red1[3];
        }
        return;
    }

    __shared__ u64 sh[256 * 8];   // 16 KB
    const int b    = blockIdx.x >> 2;
    const int seg  = blockIdx.x & 3;
    const int slen = (C + 3) >> 2;
    const int cbeg = seg * slen;
    const int cend = min(cbeg + slen, C);
    const float* row = sims + (size_t)b * C;

    u64 ls[8];
    #pragma unroll
    for (int j = 0; j < 8; ++j) ls[j] = 0ull;

    int c = cbeg + t;
    for (; c + 7 * 256 < cend; c += 8 * 256) {     // 8 independent loads first
        float v[8];
        #pragma unroll
        for (int u = 0; u < 8; ++u) v[u] = row[c + u * 256];
        #pragma unroll
        for (int u = 0; u < 8; ++u) insert8(ls, make_key(v[u], c + u * 256));
    }
    for (; c < cend; c += 256) insert8(ls, make_key(row[c], c));

    #pragma unroll
    for (int j = 0; j < 8; ++j) sh[t * 8 + j] = ls[j];
    __syncthreads();

    if (t < 64) {
        u64 m[8];
        #pragma unroll
        for (int j = 0; j < 8; ++j) m[j] = 0ull;
        for (int tt = 0; tt < 4; ++tt) {
            const u64* pp = &sh[(t * 4 + tt) * 8];
            #pragma unroll
            for (int j = 0; j < 8; ++j) {
                u64 k = pp[j];
                if (k <= m[7]) break;           // pp[] sorted descending
                m[7] = k;
                #pragma unroll
                for (int q = 7; q > 0; --q)
                    if (m[q] > m[q-1]) { u64 tmp = m[q]; m[q] = m[q-1]; m[q-1] = tmp; }
            }
        }
        for (int r = 0; r < 8; ++r) {
            u64 best = m[0];
            #pragma unroll
            for (int off = 32; off; off >>= 1) {
                u64 o = __shfl_xor(best, off, 64);
                if (o > best) best = o;
            }
            if (m[0] == best) {                 // unique owner pops
                #pragma unroll
                for (int q = 0; q < 7; ++q) m[q] = m[q+1];
                m[7] = 0ull;
            }
            if (t == 0) cand[((size_t)b * 4 + seg) * 8 + r] = best;
        }
    }
}

// ---------------------------------------------------------------------------
// Kernel 3 (gather): TWO blocks per (b, j). Each block merges b's 32 segment
// candidates in-register (broadcast loads) -> rank-j key gives episode index
// AND score (h==0,t==0 writes the score). Then copies its half episode.
// ---------------------------------------------------------------------------
__global__ __launch_bounds__(256)
void gather_kernel(const float* __restrict__ episodes,    // [C][S][256]
                   const float* __restrict__ compressed,  // [C][Cs][256]
                   const void* __restrict__ is_comp,
                   const u64* __restrict__ cand,          // [B][4][8]
                   const int* __restrict__ flags,
                   float* __restrict__ out,               // [B*8][S*256]
                   float* __restrict__ scores_out,        // [B*8]
                   int S, int Cs) {
    const int bj = blockIdx.x >> 1;
    const int h  = blockIdx.x & 1;
    const int b  = bj >> 3;
    const int j  = bj & 7;

    // merge 32 candidate keys -> top-8 (sorted desc); rank j = ls[j]
    const u64* cb = cand + (size_t)b * 32;
    u64 ls[8];
    #pragma unroll
    for (int q = 0; q < 8; ++q) ls[q] = 0ull;
    #pragma unroll
    for (int i = 0; i < 32; ++i) insert8(ls, cb[i]);

    const u64 kj  = ls[j];
    const int idx = key_idx(kj);
    if (h == 0 && threadIdx.x == 0) scores_out[bj] = key_val(kj);

    const int f_off = flags[0], f_gt1 = flags[1];
    bool comp;
    if      (f_gt1) comp = ((const float*)is_comp)[idx] != 0.f;
    else if (f_off) comp = ((const unsigned char*)is_comp)[idx] != 0;
    else            comp = ((const int*)is_comp)[idx] != 0;

    const int n4   = S * H4;       // 2048
    const int c4   = Cs * H4;      // 1024
    const int half = n4 >> 1;      // 1024
    const int v0   = h * half;

    const float4* full4 = (const float4*)episodes   + (size_t)idx * n4;
    const float4* cmp4  = (const float4*)compressed + (size_t)idx * c4;
    float4* out4 = (float4*)out + (size_t)bj * n4;
    const float4 z = make_float4(0.f, 0.f, 0.f, 0.f);

    if (comp) {
        #pragma unroll 4
        for (int v = v0 + threadIdx.x; v < v0 + half; v += 256)
            out4[v] = (v < c4) ? cmp4[v] : z;
    } else {
        #pragma unroll 4
        for (int v = v0 + threadIdx.x; v < v0 + half; v += 256)
            out4[v] = full4[v];
    }
}

// ---------------------------------------------------------------------------
extern "C" void kernel_launch(void* const* d_in, const int* in_sizes, int n_in,
                              void* d_out, int out_size, void* d_ws, size_t ws_size,
                              hipStream_t stream) {
    const float* query      = (const float*)d_in[0];
    const float* episodes   = (const float*)d_in[1];
    const float* compressed = (const float*)d_in[2];
    const float* emb        = (const float*)d_in[3];
    const void*  is_comp    = d_in[4];
    // d_in[5] is k (device scalar); fixed at 8 by the problem setup.

    const int B  = in_sizes[0] / HDIM;        // 64
    const int C  = in_sizes[3] / HDIM;        // 20000
    const int S  = in_sizes[1] / (C * HDIM);  // 32
    const int Cs = in_sizes[2] / (C * HDIM);  // 16
    const int K  = 8;

    float* out        = (float*)d_out;
    float* scores_out = out + (size_t)B * K * S * HDIM;

    // scratch layout in d_ws (fully rewritten every call -> deterministic):
    float* sims    = (float*)d_ws;                             // B*C floats
    size_t simsOff = (((size_t)B * C * sizeof(float)) + 255) & ~(size_t)255;
    u64*   cand    = (u64*)((char*)d_ws + simsOff);            // B*4*8 u64
    int*   flags   = (int*)(cand + (size_t)B * 32);            // 2 ints

    sims_kernel<<<(C + CT - 1) / CT, 256, 0, stream>>>(
        (const float4*)query, (const float4*)emb, sims, C, B);
    topk_scan<<<B * 4 + 1, 256, 0, stream>>>(sims, (const u32*)is_comp,
                                             cand, flags, C, B);
    gather_kernel<<<B * K * 2, 256, 0, stream>>>(episodes, compressed, is_comp,
                                                 cand, flags, out, scores_out,
                                                 S, Cs);
}